// Round 6
// baseline (264.953 us; speedup 1.0000x reference)
//
#include <hip/hip_runtime.h>
#include <hip/hip_bf16.h>

// Problem constants (from reference)
#define BATCH   16
#define TT      512
#define CC      768
#define D_IN    3072
#define HIDDEN  1024
#define LL      255          // (T - 4)/2 + 1
#define OUTROWS 257
#define KSTACK  12288        // D_IN * 4
#define N_DATES 16

typedef float f32x4 __attribute__((ext_vector_type(4)));
typedef __bf16 bf16x8 __attribute__((ext_vector_type(8)));
typedef unsigned short u16;

// round-to-nearest-even f32 -> bf16 bits
__device__ __forceinline__ u16 f2bf(float f) {
    unsigned u = __builtin_bit_cast(unsigned, f);
    u = (u + 0x7FFFu + ((u >> 16) & 1u)) >> 16;
    return (u16)u;
}

__device__ __forceinline__ bf16x8 lds_read8(const u16* p) {
    return __builtin_bit_cast(bf16x8, *(const uint4*)p);
}

// async global->LDS, 16B per lane. LDS dest is wave-uniform base (+lane*16 by HW),
// global src is per-lane.
__device__ __forceinline__ void gload16(const u16* g, u16* l) {
    __builtin_amdgcn_global_load_lds(
        (const __attribute__((address_space(1))) void*)g,
        (__attribute__((address_space(3))) void*)l, 16, 0, 0);
}

// ---------------- W_stack f32 -> bf16 ----------------
__global__ __launch_bounds__(256) void cvt_wstack(const float* __restrict__ W, u16* __restrict__ out) {
    size_t i = ((size_t)blockIdx.x * 256 + threadIdx.x) * 4;
    size_t stride = (size_t)gridDim.x * 256 * 4;
    for (; i < (size_t)HIDDEN * KSTACK; i += stride) {
        float4 v = *(const float4*)(W + i);
        ushort4 o = make_ushort4(f2bf(v.x), f2bf(v.y), f2bf(v.z), f2bf(v.w));
        *(ushort4*)(out + i) = o;
    }
}

// ---------------- spikes f32 -> bf16 ----------------
__global__ __launch_bounds__(256) void cvt_spikes(const float* __restrict__ in, u16* __restrict__ out) {
    size_t i = ((size_t)blockIdx.x * 256 + threadIdx.x) * 4;
    size_t stride = (size_t)gridDim.x * 256 * 4;
    for (; i < (size_t)BATCH * TT * CC; i += stride) {
        float4 v = *(const float4*)(in + i);
        ushort4 o = make_ushort4(f2bf(v.x), f2bf(v.y), f2bf(v.z), f2bf(v.w));
        *(ushort4*)(out + i) = o;
    }
}

// ---------------- which dates are used ----------------
__global__ __launch_bounds__(64) void date_flags(const int* __restrict__ date_idx, int* __restrict__ flags) {
    const int tid = threadIdx.x;
    if (tid < N_DATES) flags[tid] = 0;
    __syncthreads();
    if (tid < BATCH) flags[date_idx[tid]] = 1;
}

// ---------------- W_embed f32 -> bf16 (used dates only) ----------------
__global__ __launch_bounds__(256) void cvt_wembed(const float* __restrict__ W,
                                                  const int* __restrict__ flags,
                                                  u16* __restrict__ out) {
    const int date = blockIdx.y;
    if (!flags[date]) return;
    const size_t bofs = (size_t)date * D_IN * CC;
    const size_t i = bofs + ((size_t)blockIdx.x * 256 + threadIdx.x) * 4;
    float4 v = *(const float4*)(W + i);
    ushort4 o = make_ushort4(f2bf(v.x), f2bf(v.y), f2bf(v.z), f2bf(v.w));
    *(ushort4*)(out + i) = o;
}

// ---------------- GEMM1 (bf16 path): 256x256 tile, 8 waves, 2-deep pipeline ----------------
// x1 = gelu(spikes_bf @ Wemb_bf[date]^T + b_embed) * 32.  M=512, N=3072, K=768 per batch.
// Identical K-loop schedule to gemm2 (verified round 5).
__global__ __launch_bounds__(512, 2) void gemm1_bf(const u16* __restrict__ spk,
                                                   const u16* __restrict__ wemb,
                                                   const float* __restrict__ b_embed,
                                                   const int* __restrict__ date_idx,
                                                   u16* __restrict__ x1) {
    const int m0 = blockIdx.x * 256;   // t tile (0,256)
    const int n0 = blockIdx.y * 256;   // d tile (12)
    const int bb = blockIdx.z;
    const int date = date_idx[bb];
    const u16* A  = spk  + (size_t)bb   * TT * CC;
    const u16* Bw = wemb + (size_t)date * D_IN * CC;
    const int nt = CC / 64;            // 12 K-steps

    __shared__ u16 Asm[2 * 256 * 64];
    __shared__ u16 Bsm[2 * 256 * 64];

    const int tid  = threadIdx.x;
    const int lane = tid & 63;
    const int wave = tid >> 6;
    const int wm = wave >> 2;          // 0..1
    const int wn = wave & 3;           // 0..3

    const int lrow = lane >> 3;
    const int scol = ((lane & 7) ^ lrow) << 3;

    f32x4 acc[8][4] = {};

    auto STAGE = [&](int k0, int buf) {
        u16* Ad = Asm + buf * (256 * 64);
        u16* Bd = Bsm + buf * (256 * 64);
        #pragma unroll
        for (int i = 0; i < 4; ++i) {
            const int rb = i * 8 + wave;
            const int row = rb * 8 + lrow;
            gload16(A  + (size_t)(m0 + row) * CC + k0 + scol, Ad + rb * 512);
            gload16(Bw + (size_t)(n0 + row) * CC + k0 + scol, Bd + rb * 512);
        }
    };

    STAGE(0, 0);
    STAGE(64, 1);

    for (int t = 0; t < nt; ++t) {
        const int cur = t & 1;
        if (t + 1 < nt) { asm volatile("s_waitcnt vmcnt(8)" ::: "memory"); }
        else            { asm volatile("s_waitcnt vmcnt(0)" ::: "memory"); }
        __builtin_amdgcn_s_barrier();
        asm volatile("" ::: "memory");

        const u16* Ab = Asm + cur * (256 * 64);
        const u16* Bb = Bsm + cur * (256 * 64);
        #pragma unroll
        for (int kk = 0; kk < 64; kk += 32) {
            bf16x8 af[8], bfr[4];
            const int krow = lane & 15;
            const int kcol = kk + ((lane >> 4) << 3);
            #pragma unroll
            for (int i = 0; i < 8; ++i) {
                const int ra = wm * 128 + i * 16 + krow;
                af[i] = lds_read8(&Ab[ra * 64 + (kcol ^ ((ra & 7) << 3))]);
            }
            #pragma unroll
            for (int j = 0; j < 4; ++j) {
                const int rb2 = wn * 64 + j * 16 + krow;
                bfr[j] = lds_read8(&Bb[rb2 * 64 + (kcol ^ ((rb2 & 7) << 3))]);
            }
            #pragma unroll
            for (int i = 0; i < 8; ++i)
                #pragma unroll
                for (int j = 0; j < 4; ++j)
                    acc[i][j] = __builtin_amdgcn_mfma_f32_16x16x32_bf16(af[i], bfr[j], acc[i][j], 0, 0, 0);
        }

        asm volatile("" ::: "memory");
        __builtin_amdgcn_s_barrier();
        asm volatile("" ::: "memory");
        if (t + 2 < nt) STAGE((t + 2) * 64, cur);
    }

    // epilogue: + b_embed, exact gelu, * 32, store bf16
    const float* be = b_embed + (size_t)date * D_IN;
    #pragma unroll
    for (int i = 0; i < 8; ++i) {
        #pragma unroll
        for (int j = 0; j < 4; ++j) {
            const int col  = n0 + wn * 64 + j * 16 + (lane & 15);
            const float bias = be[col];
            const int rbase = m0 + wm * 128 + i * 16 + ((lane >> 4) << 2);
            #pragma unroll
            for (int q = 0; q < 4; ++q) {
                float v = acc[i][j][q] + bias;
                float g = 0.5f * v * (1.0f + erff(v * 0.70710678118654752f)) * 32.0f;
                x1[(size_t)bb * TT * D_IN + (size_t)(rbase + q) * D_IN + col] = f2bf(g);
            }
        }
    }
}

// ---------------- GEMM1 (f32 fallback): round-5 version ----------------
__global__ __launch_bounds__(256) void gemm1_f32(const float* __restrict__ spikes,
                                                 const float* __restrict__ W_embed,
                                                 const float* __restrict__ b_embed,
                                                 const int* __restrict__ date_idx,
                                                 u16* __restrict__ x1) {
    const int m0 = blockIdx.x * 128;
    const int n0 = blockIdx.y * 128;
    const int bb = blockIdx.z;
    const int date = date_idx[bb];
    const float* A  = spikes  + (size_t)bb  * TT * CC;
    const float* Bw = W_embed + (size_t)date * D_IN * CC;

    __shared__ u16 As[128 * 64];
    __shared__ u16 Bs[128 * 64];

    const int tid  = threadIdx.x;
    const int lane = tid & 63;
    const int wave = tid >> 6;
    const int wm = wave >> 1, wn = wave & 1;

    f32x4 acc[4][4] = {};

    for (int k0 = 0; k0 < CC; k0 += 64) {
        {
            const int c4 = tid & 15;
            int r = tid >> 4;
            #pragma unroll
            for (int p = 0; p < 8; ++p, r += 16) {
                float4 va = *(const float4*)(A  + (size_t)(m0 + r) * CC + k0 + c4 * 4);
                float4 vb = *(const float4*)(Bw + (size_t)(n0 + r) * CC + k0 + c4 * 4);
                const int col = c4 * 4;
                const int idx = r * 64 + (col ^ ((r & 7) << 3));
                *(ushort4*)(&As[idx]) = make_ushort4(f2bf(va.x), f2bf(va.y), f2bf(va.z), f2bf(va.w));
                *(ushort4*)(&Bs[idx]) = make_ushort4(f2bf(vb.x), f2bf(vb.y), f2bf(vb.z), f2bf(vb.w));
            }
        }
        __syncthreads();
        #pragma unroll
        for (int kk = 0; kk < 64; kk += 32) {
            bf16x8 af[4], bfr[4];
            const int krow = lane & 15;
            const int kcol = kk + ((lane >> 4) << 3);
            #pragma unroll
            for (int i = 0; i < 4; ++i) {
                const int ra = wm * 64 + i * 16 + krow;
                af[i]  = lds_read8(&As[ra * 64 + (kcol ^ ((ra & 7) << 3))]);
                const int rb = wn * 64 + i * 16 + krow;
                bfr[i] = lds_read8(&Bs[rb * 64 + (kcol ^ ((rb & 7) << 3))]);
            }
            #pragma unroll
            for (int i = 0; i < 4; ++i)
                #pragma unroll
                for (int j = 0; j < 4; ++j)
                    acc[i][j] = __builtin_amdgcn_mfma_f32_16x16x32_bf16(af[i], bfr[j], acc[i][j], 0, 0, 0);
        }
        __syncthreads();
    }

    const float* be = b_embed + (size_t)date * D_IN;
    #pragma unroll
    for (int i = 0; i < 4; ++i) {
        #pragma unroll
        for (int j = 0; j < 4; ++j) {
            const int col  = n0 + wn * 64 + j * 16 + (lane & 15);
            const float bias = be[col];
            const int rbase = m0 + wm * 64 + i * 16 + ((lane >> 4) << 2);
            #pragma unroll
            for (int q = 0; q < 4; ++q) {
                float v = acc[i][j][q] + bias;
                float g = 0.5f * v * (1.0f + erff(v * 0.70710678118654752f)) * 32.0f;
                x1[(size_t)bb * TT * D_IN + (size_t)(rbase + q) * D_IN + col] = f2bf(g);
            }
        }
    }
}

// ---------------- GEMM2: 256x256 tile, 8 waves, 2-deep counted-vmcnt pipeline ----------------
template <bool WRITE_PART>
__global__ __launch_bounds__(512, 2) void gemm2(const u16* __restrict__ x1,
                                                const u16* __restrict__ Wbf,
                                                float* __restrict__ part,
                                                const float* __restrict__ b_stack,
                                                const float* __restrict__ pos_table,
                                                const int* __restrict__ tstamp,
                                                float* __restrict__ out,
                                                int KS) {
    const int n0 = blockIdx.x * 256;
    const int ks = blockIdx.y;
    const int bb = blockIdx.z;
    const int KCH  = KSTACK / KS;
    const int kbeg = ks * KCH;
    const int nt   = KCH / 64;
    const u16* Xb = x1 + (size_t)bb * TT * D_IN;

    __shared__ u16 Asm[2 * 256 * 64];
    __shared__ u16 Bsm[2 * 256 * 64];

    const int tid  = threadIdx.x;
    const int lane = tid & 63;
    const int wave = tid >> 6;
    const int wm = wave >> 2;
    const int wn = wave & 3;

    const int lrow = lane >> 3;
    const int scol = ((lane & 7) ^ lrow) << 3;

    f32x4 acc[8][4] = {};

    auto STAGE = [&](int k0, int buf) {
        const int s  = k0 / D_IN;
        const int d0 = k0 % D_IN;
        u16* Ad = Asm + buf * (256 * 64);
        u16* Bd = Bsm + buf * (256 * 64);
        #pragma unroll
        for (int i = 0; i < 4; ++i) {
            const int rb = i * 8 + wave;
            const int row = rb * 8 + lrow;
            int gl = row; if (gl > LL - 1) gl = LL - 1;
            gload16(Xb + (size_t)(2 * gl + s) * D_IN + d0 + scol, Ad + rb * 512);
            gload16(Wbf + (size_t)(n0 + row) * KSTACK + k0 + scol, Bd + rb * 512);
        }
    };

    STAGE(kbeg, 0);
    STAGE(kbeg + 64, 1);

    for (int t = 0; t < nt; ++t) {
        const int cur = t & 1;
        if (t + 1 < nt) { asm volatile("s_waitcnt vmcnt(8)" ::: "memory"); }
        else            { asm volatile("s_waitcnt vmcnt(0)" ::: "memory"); }
        __builtin_amdgcn_s_barrier();
        asm volatile("" ::: "memory");

        const u16* Ab = Asm + cur * (256 * 64);
        const u16* Bb = Bsm + cur * (256 * 64);
        #pragma unroll
        for (int kk = 0; kk < 64; kk += 32) {
            bf16x8 af[8], bfr[4];
            const int krow = lane & 15;
            const int kcol = kk + ((lane >> 4) << 3);
            #pragma unroll
            for (int i = 0; i < 8; ++i) {
                const int ra = wm * 128 + i * 16 + krow;
                af[i] = lds_read8(&Ab[ra * 64 + (kcol ^ ((ra & 7) << 3))]);
            }
            #pragma unroll
            for (int j = 0; j < 4; ++j) {
                const int rb2 = wn * 64 + j * 16 + krow;
                bfr[j] = lds_read8(&Bb[rb2 * 64 + (kcol ^ ((rb2 & 7) << 3))]);
            }
            #pragma unroll
            for (int i = 0; i < 8; ++i)
                #pragma unroll
                for (int j = 0; j < 4; ++j)
                    acc[i][j] = __builtin_amdgcn_mfma_f32_16x16x32_bf16(af[i], bfr[j], acc[i][j], 0, 0, 0);
        }

        asm volatile("" ::: "memory");
        __builtin_amdgcn_s_barrier();
        asm volatile("" ::: "memory");
        if (t + 2 < nt) STAGE(kbeg + (t + 2) * 64, cur);
    }

    if (WRITE_PART) {
        float* pt = part + ((size_t)(ks * BATCH + bb) * 256) * HIDDEN;
        #pragma unroll
        for (int i = 0; i < 8; ++i) {
            #pragma unroll
            for (int j = 0; j < 4; ++j) {
                const int col = n0 + wn * 64 + j * 16 + (lane & 15);
                const int rb  = wm * 128 + i * 16 + ((lane >> 4) << 2);
                #pragma unroll
                for (int q = 0; q < 4; ++q)
                    pt[(size_t)(rb + q) * HIDDEN + col] = acc[i][j][q];
            }
        }
    } else {
        #pragma unroll
        for (int i = 0; i < 8; ++i) {
            #pragma unroll
            for (int j = 0; j < 4; ++j) {
                const int col = n0 + wn * 64 + j * 16 + (lane & 15);
                const int lb  = wm * 128 + i * 16 + ((lane >> 4) << 2);
                #pragma unroll
                for (int q = 0; q < 4; ++q) {
                    const int l = lb + q;
                    if (l < LL) {
                        const int tsv = tstamp[bb * TT + l];
                        float v = acc[i][j][q] + b_stack[col] + pos_table[(size_t)tsv * HIDDEN + col];
                        out[(size_t)bb * OUTROWS * HIDDEN + (size_t)(2 + l) * HIDDEN + col] = v;
                    }
                }
            }
        }
    }
}

// ---------------- reduce partials + bias + pos_table -> out rows 2.. ----------------
__global__ __launch_bounds__(256) void reduce_ep(const float* __restrict__ part,
                                                 const float* __restrict__ b_stack,
                                                 const float* __restrict__ pos_table,
                                                 const int* __restrict__ tstamp,
                                                 float* __restrict__ out,
                                                 int KS) {
    const int idx = blockIdx.x * 256 + threadIdx.x;
    const int c4  = idx & (HIDDEN / 4 - 1);
    const int r   = idx >> 8;
    if (r >= BATCH * LL) return;
    const int l  = r % LL;
    const int bb = r / LL;
    float4 v = make_float4(0.f, 0.f, 0.f, 0.f);
    for (int ks = 0; ks < KS; ++ks) {
        float4 p = *(const float4*)(part + ((size_t)(ks * BATCH + bb) * 256 + l) * HIDDEN + c4 * 4);
        v.x += p.x; v.y += p.y; v.z += p.z; v.w += p.w;
    }
    const int tsv = tstamp[bb * TT + l];
    float4 bs = *(const float4*)(b_stack + c4 * 4);
    float4 ps = *(const float4*)(pos_table + (size_t)tsv * HIDDEN + c4 * 4);
    v.x += bs.x + ps.x; v.y += bs.y + ps.y; v.z += bs.z + ps.z; v.w += bs.w + ps.w;
    *(float4*)(out + ((size_t)bb * OUTROWS + 2 + l) * HIDDEN + c4 * 4) = v;
}

// ---------------- rows 0/1 + mask + ts outputs ----------------
__global__ __launch_bounds__(256) void epilogue_misc(const int* __restrict__ smask,
                                                     const int* __restrict__ tstamp,
                                                     const int* __restrict__ mask_idx_p,
                                                     const int* __restrict__ session_idx_p,
                                                     const float* __restrict__ prompt_table,
                                                     const float* __restrict__ session_table,
                                                     float* __restrict__ out) {
    const int bb = blockIdx.x;
    const int tid = threadIdx.x;
    const int mi = mask_idx_p[0];
    const int si = session_idx_p[0];
    float* xb = out + (size_t)bb * OUTROWS * HIDDEN;
    for (int i = tid; i < HIDDEN; i += 256) {
        xb[i]          = session_table[(size_t)si * HIDDEN + i];
        xb[HIDDEN + i] = prompt_table[(size_t)mi * HIDDEN + i];
    }
    float* maskout = out + (size_t)BATCH * OUTROWS * HIDDEN + (size_t)bb * OUTROWS;
    float* tsout   = out + (size_t)BATCH * OUTROWS * HIDDEN + (size_t)BATCH * OUTROWS + (size_t)bb * OUTROWS;
    for (int j = tid; j < OUTROWS; j += 256) {
        if (j == 0)      { maskout[0] = 1.0f; tsout[0] = 0.0f; }
        else if (j == 1) { maskout[1] = 1.0f; tsout[1] = 1.0f; }
        else {
            const int l = j - 2;
            int m = 1;
            #pragma unroll
            for (int s = 0; s < 4; ++s) m *= smask[bb * TT + 2 * l + s];
            maskout[j] = (float)m;
            tsout[j]   = (float)(tstamp[bb * TT + l] + 2);
        }
    }
}

extern "C" void kernel_launch(void* const* d_in, const int* in_sizes, int n_in,
                              void* d_out, int out_size, void* d_ws, size_t ws_size,
                              hipStream_t stream) {
    const float* spikes      = (const float*)d_in[0];
    const int*   spikes_mask = (const int*)d_in[1];
    const int*   tstamp      = (const int*)d_in[2];
    const int*   date_idx    = (const int*)d_in[3];
    const int*   mask_idx    = (const int*)d_in[4];
    const int*   session_idx = (const int*)d_in[5];
    const float* W_embed     = (const float*)d_in[6];
    const float* b_embed     = (const float*)d_in[7];
    const float* W_stack     = (const float*)d_in[8];
    const float* b_stack     = (const float*)d_in[9];
    const float* pos_table   = (const float*)d_in[10];
    const float* prompt_tab  = (const float*)d_in[11];
    const float* session_tab = (const float*)d_in[12];
    float* out = (float*)d_out;

    // workspace layout:
    //   x1  bf16  : 50,331,648 B
    //   Wbf bf16  : 25,165,824 B
    //   union region at base = x1+Wbf:
    //     bf-gemm1 path (live during gemm1): flags(4KB) | spk_bf(12.6MB) | wemb_bf(75.5MB)
    //     part f32 (live during gemm2/reduce): KS * 16,777,216 B  — ALIASES the above
    const size_t X1_B   = (size_t)BATCH * TT * D_IN * 2;
    const size_t WBF_B  = (size_t)HIDDEN * KSTACK * 2;
    const size_t PART_B = (size_t)BATCH * 256 * HIDDEN * 4;
    const size_t FLAGS_B = 4096;
    const size_t SPK_B  = (size_t)BATCH * TT * CC * 2;
    const size_t WEMB_B = (size_t)N_DATES * D_IN * CC * 2;
    const size_t BASE   = X1_B + WBF_B;
    const size_t UNION_BF = FLAGS_B + SPK_B + WEMB_B;   // 88.08 MB > 4*PART_B? no: 67.1MB < 88.08MB

    u16*   x1    = (u16*)d_ws;
    u16*   Wbf   = (u16*)((char*)d_ws + X1_B);
    int*   flags = (int*)((char*)d_ws + BASE);
    u16*   spkbf = (u16*)((char*)d_ws + BASE + FLAGS_B);
    u16*   wembf = (u16*)((char*)d_ws + BASE + FLAGS_B + SPK_B);
    float* part  = (float*)((char*)d_ws + BASE);

    const bool use_bf = (ws_size >= BASE + UNION_BF);   // bf path implies KS=4 fits (67MB < 88MB)
    int KS = 0;
    if (use_bf) KS = 4;
    else {
        size_t rem = (ws_size > BASE) ? (ws_size - BASE) : 0;
        KS = (int)(rem / PART_B); if (KS > 4) KS = 4;
    }

    cvt_wstack<<<2048, 256, 0, stream>>>(W_stack, Wbf);

    if (use_bf) {
        date_flags<<<1, 64, 0, stream>>>(date_idx, flags);
        cvt_spikes<<<2048, 256, 0, stream>>>(spikes, spkbf);
        cvt_wembed<<<dim3(D_IN * CC / 4 / 256, N_DATES), 256, 0, stream>>>(W_embed, flags, wembf);
        gemm1_bf<<<dim3(TT / 256, D_IN / 256, BATCH), 512, 0, stream>>>(spkbf, wembf, b_embed, date_idx, x1);
    } else {
        gemm1_f32<<<dim3(TT / 128, D_IN / 128, BATCH), 256, 0, stream>>>(spikes, W_embed, b_embed, date_idx, x1);
    }

    if (KS > 0) {
        gemm2<true><<<dim3(HIDDEN / 256, KS, BATCH), 512, 0, stream>>>(x1, Wbf, part, b_stack, pos_table, tstamp, out, KS);
        reduce_ep<<<(BATCH * LL * (HIDDEN / 4) + 255) / 256, 256, 0, stream>>>(part, b_stack, pos_table, tstamp, out, KS);
    } else {
        gemm2<false><<<dim3(HIDDEN / 256, 1, BATCH), 512, 0, stream>>>(x1, Wbf, part, b_stack, pos_table, tstamp, out, 1);
    }
    epilogue_misc<<<BATCH, 256, 0, stream>>>(spikes_mask, tstamp, mask_idx, session_idx,
                                             prompt_tab, session_tab, out);
}

// Round 7
// 246.088 us; speedup vs baseline: 1.0767x; 1.0767x over previous
//
#include <hip/hip_runtime.h>
#include <hip/hip_bf16.h>

// Problem constants (from reference)
#define BATCH   16
#define TT      512
#define CC      768
#define D_IN    3072
#define HIDDEN  1024
#define LL      255          // (T - 4)/2 + 1
#define OUTROWS 257
#define KSTACK  12288        // D_IN * 4
#define N_DATES 16

typedef float f32x4 __attribute__((ext_vector_type(4)));
typedef __bf16 bf16x8 __attribute__((ext_vector_type(8)));
typedef unsigned short u16;

// round-to-nearest-even f32 -> bf16 bits
__device__ __forceinline__ u16 f2bf(float f) {
    unsigned u = __builtin_bit_cast(unsigned, f);
    u = (u + 0x7FFFu + ((u >> 16) & 1u)) >> 16;
    return (u16)u;
}

__device__ __forceinline__ bf16x8 lds_read8(const u16* p) {
    return __builtin_bit_cast(bf16x8, *(const uint4*)p);
}

// async global->LDS, 16B per lane. LDS dest is wave-uniform base (+lane*16 by HW),
// global src is per-lane.
__device__ __forceinline__ void gload16(const u16* g, u16* l) {
    __builtin_amdgcn_global_load_lds(
        (const __attribute__((address_space(1))) void*)g,
        (__attribute__((address_space(3))) void*)l, 16, 0, 0);
}

// ---------------- W_stack f32 -> bf16 ----------------
__global__ __launch_bounds__(256) void cvt_wstack(const float* __restrict__ W, u16* __restrict__ out) {
    size_t i = ((size_t)blockIdx.x * 256 + threadIdx.x) * 4;
    size_t stride = (size_t)gridDim.x * 256 * 4;
    for (; i < (size_t)HIDDEN * KSTACK; i += stride) {
        float4 v = *(const float4*)(W + i);
        ushort4 o = make_ushort4(f2bf(v.x), f2bf(v.y), f2bf(v.z), f2bf(v.w));
        *(ushort4*)(out + i) = o;
    }
}

// ---------------- spikes f32 -> bf16 ----------------
__global__ __launch_bounds__(256) void cvt_spikes(const float* __restrict__ in, u16* __restrict__ out) {
    size_t i = ((size_t)blockIdx.x * 256 + threadIdx.x) * 4;
    size_t stride = (size_t)gridDim.x * 256 * 4;
    for (; i < (size_t)BATCH * TT * CC; i += stride) {
        float4 v = *(const float4*)(in + i);
        ushort4 o = make_ushort4(f2bf(v.x), f2bf(v.y), f2bf(v.z), f2bf(v.w));
        *(ushort4*)(out + i) = o;
    }
}

// ---------------- which dates are used ----------------
__global__ __launch_bounds__(64) void date_flags(const int* __restrict__ date_idx, int* __restrict__ flags) {
    const int tid = threadIdx.x;
    if (tid < N_DATES) flags[tid] = 0;
    __syncthreads();
    if (tid < BATCH) flags[date_idx[tid]] = 1;
}

// ---------------- W_embed f32 -> bf16 (used dates only) ----------------
__global__ __launch_bounds__(256) void cvt_wembed(const float* __restrict__ W,
                                                  const int* __restrict__ flags,
                                                  u16* __restrict__ out) {
    const int date = blockIdx.y;
    if (!flags[date]) return;
    const size_t bofs = (size_t)date * D_IN * CC;
    const size_t i = bofs + ((size_t)blockIdx.x * 256 + threadIdx.x) * 4;
    float4 v = *(const float4*)(W + i);
    ushort4 o = make_ushort4(f2bf(v.x), f2bf(v.y), f2bf(v.z), f2bf(v.w));
    *(ushort4*)(out + i) = o;
}

// ---------------- GEMM1 (bf16 path): 256x256 tile, 8 waves, 2-deep pipeline ----------------
// Unchanged from round 6 (verified).
__global__ __launch_bounds__(512, 2) void gemm1_bf(const u16* __restrict__ spk,
                                                   const u16* __restrict__ wemb,
                                                   const float* __restrict__ b_embed,
                                                   const int* __restrict__ date_idx,
                                                   u16* __restrict__ x1) {
    const int m0 = blockIdx.x * 256;
    const int n0 = blockIdx.y * 256;
    const int bb = blockIdx.z;
    const int date = date_idx[bb];
    const u16* A  = spk  + (size_t)bb   * TT * CC;
    const u16* Bw = wemb + (size_t)date * D_IN * CC;
    const int nt = CC / 64;

    __shared__ u16 Asm[2 * 256 * 64];
    __shared__ u16 Bsm[2 * 256 * 64];

    const int tid  = threadIdx.x;
    const int lane = tid & 63;
    const int wave = tid >> 6;
    const int wm = wave >> 2;
    const int wn = wave & 3;

    const int lrow = lane >> 3;
    const int scol = ((lane & 7) ^ lrow) << 3;

    f32x4 acc[8][4] = {};

    auto STAGE = [&](int k0, int buf) {
        u16* Ad = Asm + buf * (256 * 64);
        u16* Bd = Bsm + buf * (256 * 64);
        #pragma unroll
        for (int i = 0; i < 4; ++i) {
            const int rb = i * 8 + wave;
            const int row = rb * 8 + lrow;
            gload16(A  + (size_t)(m0 + row) * CC + k0 + scol, Ad + rb * 512);
            gload16(Bw + (size_t)(n0 + row) * CC + k0 + scol, Bd + rb * 512);
        }
    };

    STAGE(0, 0);
    STAGE(64, 1);

    for (int t = 0; t < nt; ++t) {
        const int cur = t & 1;
        if (t + 1 < nt) { asm volatile("s_waitcnt vmcnt(8)" ::: "memory"); }
        else            { asm volatile("s_waitcnt vmcnt(0)" ::: "memory"); }
        __builtin_amdgcn_s_barrier();
        asm volatile("" ::: "memory");

        const u16* Ab = Asm + cur * (256 * 64);
        const u16* Bb = Bsm + cur * (256 * 64);
        #pragma unroll
        for (int kk = 0; kk < 64; kk += 32) {
            bf16x8 af[8], bfr[4];
            const int krow = lane & 15;
            const int kcol = kk + ((lane >> 4) << 3);
            #pragma unroll
            for (int i = 0; i < 8; ++i) {
                const int ra = wm * 128 + i * 16 + krow;
                af[i] = lds_read8(&Ab[ra * 64 + (kcol ^ ((ra & 7) << 3))]);
            }
            #pragma unroll
            for (int j = 0; j < 4; ++j) {
                const int rb2 = wn * 64 + j * 16 + krow;
                bfr[j] = lds_read8(&Bb[rb2 * 64 + (kcol ^ ((rb2 & 7) << 3))]);
            }
            #pragma unroll
            for (int i = 0; i < 8; ++i)
                #pragma unroll
                for (int j = 0; j < 4; ++j)
                    acc[i][j] = __builtin_amdgcn_mfma_f32_16x16x32_bf16(af[i], bfr[j], acc[i][j], 0, 0, 0);
        }

        asm volatile("" ::: "memory");
        __builtin_amdgcn_s_barrier();
        asm volatile("" ::: "memory");
        if (t + 2 < nt) STAGE((t + 2) * 64, cur);
    }

    const float* be = b_embed + (size_t)date * D_IN;
    #pragma unroll
    for (int i = 0; i < 8; ++i) {
        #pragma unroll
        for (int j = 0; j < 4; ++j) {
            const int col  = n0 + wn * 64 + j * 16 + (lane & 15);
            const float bias = be[col];
            const int rbase = m0 + wm * 128 + i * 16 + ((lane >> 4) << 2);
            #pragma unroll
            for (int q = 0; q < 4; ++q) {
                float v = acc[i][j][q] + bias;
                float g = 0.5f * v * (1.0f + erff(v * 0.70710678118654752f)) * 32.0f;
                x1[(size_t)bb * TT * D_IN + (size_t)(rbase + q) * D_IN + col] = f2bf(g);
            }
        }
    }
}

// ---------------- GEMM1 (f32 fallback) ----------------
__global__ __launch_bounds__(256) void gemm1_f32(const float* __restrict__ spikes,
                                                 const float* __restrict__ W_embed,
                                                 const float* __restrict__ b_embed,
                                                 const int* __restrict__ date_idx,
                                                 u16* __restrict__ x1) {
    const int m0 = blockIdx.x * 128;
    const int n0 = blockIdx.y * 128;
    const int bb = blockIdx.z;
    const int date = date_idx[bb];
    const float* A  = spikes  + (size_t)bb  * TT * CC;
    const float* Bw = W_embed + (size_t)date * D_IN * CC;

    __shared__ u16 As[128 * 64];
    __shared__ u16 Bs[128 * 64];

    const int tid  = threadIdx.x;
    const int lane = tid & 63;
    const int wave = tid >> 6;
    const int wm = wave >> 1, wn = wave & 1;

    f32x4 acc[4][4] = {};

    for (int k0 = 0; k0 < CC; k0 += 64) {
        {
            const int c4 = tid & 15;
            int r = tid >> 4;
            #pragma unroll
            for (int p = 0; p < 8; ++p, r += 16) {
                float4 va = *(const float4*)(A  + (size_t)(m0 + r) * CC + k0 + c4 * 4);
                float4 vb = *(const float4*)(Bw + (size_t)(n0 + r) * CC + k0 + c4 * 4);
                const int col = c4 * 4;
                const int idx = r * 64 + (col ^ ((r & 7) << 3));
                *(ushort4*)(&As[idx]) = make_ushort4(f2bf(va.x), f2bf(va.y), f2bf(va.z), f2bf(va.w));
                *(ushort4*)(&Bs[idx]) = make_ushort4(f2bf(vb.x), f2bf(vb.y), f2bf(vb.z), f2bf(vb.w));
            }
        }
        __syncthreads();
        #pragma unroll
        for (int kk = 0; kk < 64; kk += 32) {
            bf16x8 af[4], bfr[4];
            const int krow = lane & 15;
            const int kcol = kk + ((lane >> 4) << 3);
            #pragma unroll
            for (int i = 0; i < 4; ++i) {
                const int ra = wm * 64 + i * 16 + krow;
                af[i]  = lds_read8(&As[ra * 64 + (kcol ^ ((ra & 7) << 3))]);
                const int rb = wn * 64 + i * 16 + krow;
                bfr[i] = lds_read8(&Bs[rb * 64 + (kcol ^ ((rb & 7) << 3))]);
            }
            #pragma unroll
            for (int i = 0; i < 4; ++i)
                #pragma unroll
                for (int j = 0; j < 4; ++j)
                    acc[i][j] = __builtin_amdgcn_mfma_f32_16x16x32_bf16(af[i], bfr[j], acc[i][j], 0, 0, 0);
        }
        __syncthreads();
    }

    const float* be = b_embed + (size_t)date * D_IN;
    #pragma unroll
    for (int i = 0; i < 4; ++i) {
        #pragma unroll
        for (int j = 0; j < 4; ++j) {
            const int col  = n0 + wn * 64 + j * 16 + (lane & 15);
            const float bias = be[col];
            const int rbase = m0 + wm * 64 + i * 16 + ((lane >> 4) << 2);
            #pragma unroll
            for (int q = 0; q < 4; ++q) {
                float v = acc[i][j][q] + bias;
                float g = 0.5f * v * (1.0f + erff(v * 0.70710678118654752f)) * 32.0f;
                x1[(size_t)bb * TT * D_IN + (size_t)(rbase + q) * D_IN + col] = f2bf(g);
            }
        }
    }
}

// ---------------- GEMM2: 256x256 tile, 8 waves, 32-K-slice ring pipeline ----------------
// 4 LDS slots per operand, each [128 lds-rows][64 cols] row-pair packed:
//   LDS[u][c'] holds tile-row (2u + ((c'^swz(u))>>5)), k-offset ((c'^swz(u))&31), swz(u)=(u&7)<<3.
// 3 slices staged ahead; ONE barrier per slice; counted vmcnt(8) (4 loads/slice/wave,
// 2 slices left in flight); stage-issue sits between ds_reads and MFMA; setprio on MFMA.
// Safety: each wave's ds_reads of slot s are lgkm-drained by its MFMAs before it reaches
// the next barrier, so after the phase-top barrier, slot (ph+3)&3 == (ph-1)&3 is
// globally read-complete before STAGE(ph+3) issues.
template <bool WRITE_PART>
__global__ __launch_bounds__(512, 2) void gemm2(const u16* __restrict__ x1,
                                                const u16* __restrict__ Wbf,
                                                float* __restrict__ part,
                                                const float* __restrict__ b_stack,
                                                const float* __restrict__ pos_table,
                                                const int* __restrict__ tstamp,
                                                float* __restrict__ out,
                                                int KS) {
    const int n0 = blockIdx.x * 256;
    const int ks = blockIdx.y;
    const int bb = blockIdx.z;
    const int KCH  = KSTACK / KS;
    const int kbeg = ks * KCH;
    const int S    = KCH / 32;           // number of 32-wide K slices
    const u16* Xb = x1 + (size_t)bb * TT * D_IN;

    __shared__ u16 Asm[4][128 * 64];     // 64 KiB
    __shared__ u16 Bsm[4][128 * 64];     // 64 KiB

    const int tid  = threadIdx.x;
    const int lane = tid & 63;
    const int wave = tid >> 6;           // 0..7
    const int wm = wave >> 2;            // 0..1 (M half)
    const int wn = wave & 3;             // 0..3 (N quarter)

    // staging lane mapping: per issue, 64 lanes x 16B = 8 LDS rows x 64 cols (linear dest).
    // inverse-swizzled source col selects (tile-row parity, k-offset):
    const int lrow  = lane >> 3;                  // LDS row within 8-row group (== u&7)
    const int scol  = ((lane & 7) ^ lrow) << 3;   // pre-swizzled col in 64-space
    const int chalf = scol >> 5;                  // which packed tile row (0/1)
    const int gk    = scol & 31;                  // k offset within slice

    f32x4 acc[8][4] = {};

    auto STAGE = [&](int slice) {
        const int slot = slice & 3;
        const int k0 = kbeg + slice * 32;
        const int s  = k0 / D_IN;        // window slot (32 | 3072, never straddles)
        const int d0 = k0 % D_IN;
        u16* Ad = Asm[slot];
        u16* Bd = Bsm[slot];
        #pragma unroll
        for (int p = 0; p < 2; ++p) {
            const int rbase = (wave + 8 * p) * 8;    // 8 LDS rows per issue
            const int u  = rbase + lrow;             // LDS row 0..127
            const int tr = 2 * u + chalf;            // tile row 0..255
            int gl = tr; if (gl > LL - 1) gl = LL - 1;
            gload16(Xb + (size_t)(2 * gl + s) * D_IN + d0 + gk, Ad + rbase * 64);
            gload16(Wbf + (size_t)(n0 + tr) * KSTACK + k0 + gk, Bd + rbase * 64);
        }
    };

    // prologue: 3 slices in flight (12 loads/wave)
    STAGE(0); STAGE(1); STAGE(2);

    const int krow  = lane & 15;
    const int kcol  = (lane >> 4) << 3;                            // 0,8,16,24
    const int cfrag = (kcol + ((krow & 1) << 5)) ^ ((krow >> 1) << 3);
    const int urow  = krow >> 1;

    for (int ph = 0; ph < S; ++ph) {
        if (ph < S - 2)       { asm volatile("s_waitcnt vmcnt(8)" ::: "memory"); }
        else if (ph == S - 2) { asm volatile("s_waitcnt vmcnt(4)" ::: "memory"); }
        else                  { asm volatile("s_waitcnt vmcnt(0)" ::: "memory"); }
        __builtin_amdgcn_s_barrier();
        asm volatile("" ::: "memory");

        const u16* Ab = Asm[ph & 3];
        const u16* Bb = Bsm[ph & 3];
        bf16x8 af[8], bfr[4];
        #pragma unroll
        for (int i = 0; i < 8; ++i)
            af[i] = lds_read8(&Ab[(wm * 64 + i * 8 + urow) * 64 + cfrag]);
        #pragma unroll
        for (int j = 0; j < 4; ++j)
            bfr[j] = lds_read8(&Bb[(wn * 32 + j * 8 + urow) * 64 + cfrag]);

        if (ph + 3 < S) STAGE(ph + 3);   // writes slot (ph-1)&3: read-complete per barrier above

        __builtin_amdgcn_s_setprio(1);
        #pragma unroll
        for (int i = 0; i < 8; ++i)
            #pragma unroll
            for (int j = 0; j < 4; ++j)
                acc[i][j] = __builtin_amdgcn_mfma_f32_16x16x32_bf16(af[i], bfr[j], acc[i][j], 0, 0, 0);
        __builtin_amdgcn_s_setprio(0);
    }

    if (WRITE_PART) {
        float* pt = part + ((size_t)(ks * BATCH + bb) * 256) * HIDDEN;
        #pragma unroll
        for (int i = 0; i < 8; ++i) {
            #pragma unroll
            for (int j = 0; j < 4; ++j) {
                const int col = n0 + wn * 64 + j * 16 + (lane & 15);
                const int rb  = wm * 128 + i * 16 + ((lane >> 4) << 2);
                #pragma unroll
                for (int q = 0; q < 4; ++q)
                    pt[(size_t)(rb + q) * HIDDEN + col] = acc[i][j][q];
            }
        }
    } else {
        #pragma unroll
        for (int i = 0; i < 8; ++i) {
            #pragma unroll
            for (int j = 0; j < 4; ++j) {
                const int col = n0 + wn * 64 + j * 16 + (lane & 15);
                const int lb  = wm * 128 + i * 16 + ((lane >> 4) << 2);
                #pragma unroll
                for (int q = 0; q < 4; ++q) {
                    const int l = lb + q;
                    if (l < LL) {
                        const int tsv = tstamp[bb * TT + l];
                        float v = acc[i][j][q] + b_stack[col] + pos_table[(size_t)tsv * HIDDEN + col];
                        out[(size_t)bb * OUTROWS * HIDDEN + (size_t)(2 + l) * HIDDEN + col] = v;
                    }
                }
            }
        }
    }
}

// ---------------- reduce partials + bias + pos_table -> out rows 2.. ----------------
__global__ __launch_bounds__(256) void reduce_ep(const float* __restrict__ part,
                                                 const float* __restrict__ b_stack,
                                                 const float* __restrict__ pos_table,
                                                 const int* __restrict__ tstamp,
                                                 float* __restrict__ out,
                                                 int KS) {
    const int idx = blockIdx.x * 256 + threadIdx.x;
    const int c4  = idx & (HIDDEN / 4 - 1);
    const int r   = idx >> 8;
    if (r >= BATCH * LL) return;
    const int l  = r % LL;
    const int bb = r / LL;
    float4 v = make_float4(0.f, 0.f, 0.f, 0.f);
    for (int ks = 0; ks < KS; ++ks) {
        float4 p = *(const float4*)(part + ((size_t)(ks * BATCH + bb) * 256 + l) * HIDDEN + c4 * 4);
        v.x += p.x; v.y += p.y; v.z += p.z; v.w += p.w;
    }
    const int tsv = tstamp[bb * TT + l];
    float4 bs = *(const float4*)(b_stack + c4 * 4);
    float4 ps = *(const float4*)(pos_table + (size_t)tsv * HIDDEN + c4 * 4);
    v.x += bs.x + ps.x; v.y += bs.y + ps.y; v.z += bs.z + ps.z; v.w += bs.w + ps.w;
    *(float4*)(out + ((size_t)bb * OUTROWS + 2 + l) * HIDDEN + c4 * 4) = v;
}

// ---------------- rows 0/1 + mask + ts outputs ----------------
__global__ __launch_bounds__(256) void epilogue_misc(const int* __restrict__ smask,
                                                     const int* __restrict__ tstamp,
                                                     const int* __restrict__ mask_idx_p,
                                                     const int* __restrict__ session_idx_p,
                                                     const float* __restrict__ prompt_table,
                                                     const float* __restrict__ session_table,
                                                     float* __restrict__ out) {
    const int bb = blockIdx.x;
    const int tid = threadIdx.x;
    const int mi = mask_idx_p[0];
    const int si = session_idx_p[0];
    float* xb = out + (size_t)bb * OUTROWS * HIDDEN;
    for (int i = tid; i < HIDDEN; i += 256) {
        xb[i]          = session_table[(size_t)si * HIDDEN + i];
        xb[HIDDEN + i] = prompt_table[(size_t)mi * HIDDEN + i];
    }
    float* maskout = out + (size_t)BATCH * OUTROWS * HIDDEN + (size_t)bb * OUTROWS;
    float* tsout   = out + (size_t)BATCH * OUTROWS * HIDDEN + (size_t)BATCH * OUTROWS + (size_t)bb * OUTROWS;
    for (int j = tid; j < OUTROWS; j += 256) {
        if (j == 0)      { maskout[0] = 1.0f; tsout[0] = 0.0f; }
        else if (j == 1) { maskout[1] = 1.0f; tsout[1] = 1.0f; }
        else {
            const int l = j - 2;
            int m = 1;
            #pragma unroll
            for (int s = 0; s < 4; ++s) m *= smask[bb * TT + 2 * l + s];
            maskout[j] = (float)m;
            tsout[j]   = (float)(tstamp[bb * TT + l] + 2);
        }
    }
}

extern "C" void kernel_launch(void* const* d_in, const int* in_sizes, int n_in,
                              void* d_out, int out_size, void* d_ws, size_t ws_size,
                              hipStream_t stream) {
    const float* spikes      = (const float*)d_in[0];
    const int*   spikes_mask = (const int*)d_in[1];
    const int*   tstamp      = (const int*)d_in[2];
    const int*   date_idx    = (const int*)d_in[3];
    const int*   mask_idx    = (const int*)d_in[4];
    const int*   session_idx = (const int*)d_in[5];
    const float* W_embed     = (const float*)d_in[6];
    const float* b_embed     = (const float*)d_in[7];
    const float* W_stack     = (const float*)d_in[8];
    const float* b_stack     = (const float*)d_in[9];
    const float* pos_table   = (const float*)d_in[10];
    const float* prompt_tab  = (const float*)d_in[11];
    const float* session_tab = (const float*)d_in[12];
    float* out = (float*)d_out;

    const size_t X1_B   = (size_t)BATCH * TT * D_IN * 2;
    const size_t WBF_B  = (size_t)HIDDEN * KSTACK * 2;
    const size_t PART_B = (size_t)BATCH * 256 * HIDDEN * 4;
    const size_t FLAGS_B = 4096;
    const size_t SPK_B  = (size_t)BATCH * TT * CC * 2;
    const size_t WEMB_B = (size_t)N_DATES * D_IN * CC * 2;
    const size_t BASE   = X1_B + WBF_B;
    const size_t UNION_BF = FLAGS_B + SPK_B + WEMB_B;

    u16*   x1    = (u16*)d_ws;
    u16*   Wbf   = (u16*)((char*)d_ws + X1_B);
    int*   flags = (int*)((char*)d_ws + BASE);
    u16*   spkbf = (u16*)((char*)d_ws + BASE + FLAGS_B);
    u16*   wembf = (u16*)((char*)d_ws + BASE + FLAGS_B + SPK_B);
    float* part  = (float*)((char*)d_ws + BASE);

    const bool use_bf = (ws_size >= BASE + UNION_BF);
    int KS = 0;
    if (use_bf) KS = 4;
    else {
        size_t rem = (ws_size > BASE) ? (ws_size - BASE) : 0;
        KS = (int)(rem / PART_B); if (KS > 4) KS = 4;
    }

    cvt_wstack<<<2048, 256, 0, stream>>>(W_stack, Wbf);

    if (use_bf) {
        date_flags<<<1, 64, 0, stream>>>(date_idx, flags);
        cvt_spikes<<<2048, 256, 0, stream>>>(spikes, spkbf);
        cvt_wembed<<<dim3(D_IN * CC / 4 / 256, N_DATES), 256, 0, stream>>>(W_embed, flags, wembf);
        gemm1_bf<<<dim3(TT / 256, D_IN / 256, BATCH), 512, 0, stream>>>(spkbf, wembf, b_embed, date_idx, x1);
    } else {
        gemm1_f32<<<dim3(TT / 128, D_IN / 128, BATCH), 256, 0, stream>>>(spikes, W_embed, b_embed, date_idx, x1);
    }

    if (KS > 0) {
        gemm2<true><<<dim3(HIDDEN / 256, KS, BATCH), 512, 0, stream>>>(x1, Wbf, part, b_stack, pos_table, tstamp, out, KS);
        reduce_ep<<<(BATCH * LL * (HIDDEN / 4) + 255) / 256, 256, 0, stream>>>(part, b_stack, pos_table, tstamp, out, KS);
    } else {
        gemm2<false><<<dim3(HIDDEN / 256, 1, BATCH), 512, 0, stream>>>(x1, Wbf, part, b_stack, pos_table, tstamp, out, 1);
    }
    epilogue_misc<<<BATCH, 256, 0, stream>>>(spikes_mask, tstamp, mask_idx, session_idx,
                                             prompt_tab, session_tab, out);
}